// Round 1
// baseline (154.871 us; speedup 1.0000x reference)
//
#include <hip/hip_runtime.h>
#include <stdint.h>
#include <limits.h>

// Problem constants (B, C, H, W fixed by the reference)
#define Bn      16
#define Nn      5242880            // 80*256*256 elements per batch
#define KK      100                // TOPK
#define BPB     128                // blocks per batch for the streaming pass
#define CHUNK   (Nn / BPB)         // 40960 elements per block
#define SLOT    24                 // per-block candidate capacity (mean ~1.3 @ T0=4.0)
#define SORTCAP 2048               // guard-path sort capacity
#define RANKCAP 256                // fast-path rank-selection capacity (mean ~166)
#define NBINS   4096               // fallback radix bins
#define T0      4.0f               // fast-path threshold (top-100 cutoff ~4.11 for N(0,1))
#define FTH     256                // block size (also finalize width)

typedef float f4v __attribute__((ext_vector_type(4)));

__device__ __forceinline__ unsigned fkey(unsigned u) {
    // monotone float->uint transform: larger float => larger key
    return (u & 0x80000000u) ? ~u : (u | 0x80000000u);
}

// ---------- emit one detection at a given rank ----------
__device__ __forceinline__ void emit_one(int b, int rank, float val, int idx,
                                         const float* __restrict__ wh,
                                         const float* __restrict__ reg,
                                         float* __restrict__ out) {
    float* out_cls = out;                 // [16][100]
    float* out_scr = out + Bn * KK;       // [16][100]
    float* out_res = out + 2 * Bn * KK;   // [16][100][4]
    out_cls[b * KK + rank] = (float)idx * (1.0f / 65536.0f);  // exact pow2 division
    out_scr[b * KK + rank] = val;
    const int s  = idx & 65535;
    const float tys = (float)s * (1.0f / 256.0f);             // topk_indices / W (exact)
    const float txs = (float)(s & 255);                       // topk_indices % W
    // reg/wh layout [B,2,H,W]: channel-c at (b, s) = ptr[(b*2+c)*65536 + s]
    const float xo = reg[(size_t)(b * 2 + 0) * 65536 + s];
    const float yo = reg[(size_t)(b * 2 + 1) * 65536 + s];
    const float ww = wh [(size_t)(b * 2 + 0) * 65536 + s];
    const float hh = wh [(size_t)(b * 2 + 1) * 65536 + s];
    const float cx = txs + xo;
    const float cy = tys + yo;
    const float hw  = ww * 0.5f;
    const float hh2 = hh * 0.5f;
    float* r = out_res + (size_t)(b * KK + rank) * 4;
    r[0] = (cx - hw)  * 4.0f;
    r[1] = (cy - hh2) * 4.0f;
    r[2] = (cx + hw)  * 4.0f;
    r[3] = (cy + hh2) * 4.0f;
}

// ---------- fused: stream-collect + last-block-per-batch finalize ------------
// LDS budget: uw 16 KiB (union of hist[4096] and {sv[2048],si[2048]}) +
// scan 512 B + scalars ~= 16.9 KiB -> 8 blocks/CU retained (threads-capped).
__global__ __launch_bounds__(FTH, 8) void k_fused(const float* __restrict__ x,
                                                  const float* __restrict__ wh,
                                                  const float* __restrict__ reg,
                                                  int* __restrict__ done,
                                                  int* __restrict__ bcnt,
                                                  float* __restrict__ cval,
                                                  int* __restrict__ cidx,
                                                  float* __restrict__ out) {
    const int b = blockIdx.y, blk = blockIdx.x;
    const int t = threadIdx.x;

    __shared__ int lcnt;
    __shared__ int amlast;
    __shared__ int uw[2 * SORTCAP];   // 16 KiB union: hist[4096] OR {sv,si}
    __shared__ int scan[BPB];
    __shared__ int sflags;
    __shared__ int scnt;
    __shared__ unsigned stk;

    // ================= collect phase (every block) =================
    if (t == 0) lcnt = 0;
    __syncthreads();
    {
        const f4v* xv = reinterpret_cast<const f4v*>(
            x + (size_t)b * Nn + (size_t)blk * CHUNK);
        const int base = blk * CHUNK;
        float* v  = cval + ((size_t)b * BPB + blk) * SLOT;
        int*   ix = cidx + ((size_t)b * BPB + blk) * SLOT;
#pragma unroll 4
        for (int j = t; j < CHUNK / 4; j += FTH) {
            f4v f = __builtin_nontemporal_load(&xv[j]);   // streaming read, no reuse
            const float m = fmaxf(fmaxf(f.x, f.y), fmaxf(f.z, f.w));
            if (m >= T0) {                                 // ~1.3e-4 per-lane: rare
                const int i0 = base + 4 * j;
                if (f.x >= T0) { int p = atomicAdd(&lcnt, 1); if (p < SLOT) { v[p] = f.x; ix[p] = i0;     } }
                if (f.y >= T0) { int p = atomicAdd(&lcnt, 1); if (p < SLOT) { v[p] = f.y; ix[p] = i0 + 1; } }
                if (f.z >= T0) { int p = atomicAdd(&lcnt, 1); if (p < SLOT) { v[p] = f.z; ix[p] = i0 + 2; } }
                if (f.w >= T0) { int p = atomicAdd(&lcnt, 1); if (p < SLOT) { v[p] = f.w; ix[p] = i0 + 3; } }
            }
        }
    }
    __syncthreads();   // drains all candidate stores (vmcnt(0) before s_barrier)
    if (t == 0) {
        bcnt[b * BPB + blk] = lcnt;
        __threadfence();   // release: candidates + bcnt flushed device-wide (wbl2 ~empty: NT loads)
        amlast = (atomicAdd(&done[b], 1) == BPB - 1) ? 1 : 0;  // device-scope ticket
    }
    __syncthreads();
    if (!amlast) return;

    // ================= finalize phase (1 block per batch) =================
    __threadfence();   // acquire: buffer_inv kills stale cross-XCD L1/L2 lines

    float* sv   = (float*)uw;          // uw[0..2047]
    int*   si   = uw + SORTCAP;        // uw[2048..4095]
    int*   hist = uw;                  // fallback phase 1 only (before sv/si init)

    if (t == 0) { sflags = 0; scnt = 0; }
    __syncthreads();

    int c = 0;
    if (t < BPB) {
        c = bcnt[b * BPB + t];
        if (c > SLOT) atomicOr(&sflags, 1);
        scan[t] = c;
    }
    __syncthreads();
    // Hillis-Steele inclusive scan over BPB counts
    for (int off = 1; off < BPB; off <<= 1) {
        int vv = 0;
        if (t < BPB) { vv = scan[t]; if (t >= off) vv += scan[t - off]; }
        __syncthreads();
        if (t < BPB) scan[t] = vv;
        __syncthreads();
    }
    const int total_all = scan[BPB - 1];
    const bool bad = (sflags != 0) || (total_all < KK) || (total_all > SORTCAP);

    const float NEG_INF = __int_as_float(0xFF800000);
    int n;
    if (!bad) {
        n = total_all;
        for (int i = t; i < SORTCAP; i += FTH) { sv[i] = NEG_INF; si[i] = INT_MAX; }
        __syncthreads();
        if (t < BPB) {
            const int off = scan[t] - c;   // exclusive prefix
            const float* v  = cval + ((size_t)b * BPB + t) * SLOT;
            const int*   ix = cidx + ((size_t)b * BPB + t) * SLOT;
            for (int i = 0; i < c; ++i) { sv[off + i] = v[i]; si[off + i] = ix[i]; }
        }
        __syncthreads();
    } else {
        // ---- robust fallback: LDS-histogram top-k over full batch (never-path)
        // Phase 1: histogram uses the whole union buffer; sv/si initialized AFTER.
        for (int i = t; i < NBINS; i += FTH) hist[i] = 0;
        __syncthreads();
        const float4* xv4 = reinterpret_cast<const float4*>(x + (size_t)b * Nn);
        for (int j = t; j < Nn / 4; j += FTH) {
            float4 f = xv4[j];
            atomicAdd(&hist[fkey(__float_as_uint(f.x)) >> 20], 1);
            atomicAdd(&hist[fkey(__float_as_uint(f.y)) >> 20], 1);
            atomicAdd(&hist[fkey(__float_as_uint(f.z)) >> 20], 1);
            atomicAdd(&hist[fkey(__float_as_uint(f.w)) >> 20], 1);
        }
        __syncthreads();
        if (t == 0) {
            int cum = 0; unsigned k2 = 0;
            for (int bin = NBINS - 1; bin >= 0; --bin) {
                cum += hist[bin];
                if (cum >= KK) { k2 = (unsigned)bin << 20; break; }
            }
            stk = k2;
        }
        __syncthreads();
        const unsigned tk = stk;
        // Phase 2: overwrite union buffer with sv/si and re-collect above threshold
        for (int i = t; i < SORTCAP; i += FTH) { sv[i] = NEG_INF; si[i] = INT_MAX; }
        __syncthreads();
        for (int j = t; j < Nn / 4; j += FTH) {
            float4 f = xv4[j];
            const int i0 = 4 * j;
            float a[4] = {f.x, f.y, f.z, f.w};
#pragma unroll
            for (int cc = 0; cc < 4; ++cc) {
                if (fkey(__float_as_uint(a[cc])) >= tk) {
                    int p = atomicAdd(&scnt, 1);
                    if (p < SORTCAP) { sv[p] = a[cc]; si[p] = i0 + cc; }
                }
            }
        }
        __syncthreads();
        n = scnt; if (n > SORTCAP) n = SORTCAP;
    }

    if (!bad && n <= RANKCAP) {
        // ---- fast path: exact rank via O(n^2) broadcast compares, 1 barrier --
        const float myv = sv[t];          // t in [0,256): own candidate (or pad)
        const int   myi = si[t];
        int rank = 0;
#pragma unroll 8
        for (int j = 0; j < RANKCAP; ++j) {
            const float vj = sv[j];       // LDS broadcast: all lanes same addr
            const int   ij = si[j];
            rank += ((vj > myv) || (vj == myv && ij < myi)) ? 1 : 0;
        }
        if (rank < KK) emit_one(b, rank, myv, myi, wh, reg, out);
        return;
    }

    // ---- guard path: bitonic sort (value desc, tie -> index asc) ------------
    int pad = FTH;
    while (pad < n) pad <<= 1;     // <= SORTCAP
    for (int k = 2; k <= pad; k <<= 1) {
        for (int j = k >> 1; j > 0; j >>= 1) {
            for (int i = t; i < pad; i += FTH) {
                const int ixj = i ^ j;
                if (ixj > i) {
                    float va = sv[i], vb = sv[ixj];
                    int   ia = si[i], ib = si[ixj];
                    const bool a_before_b = (va > vb) || (va == vb && ia < ib);
                    const bool dir = ((i & k) == 0);
                    if (dir ? !a_before_b : a_before_b) {
                        sv[i] = vb; sv[ixj] = va; si[i] = ib; si[ixj] = ia;
                    }
                }
            }
            __syncthreads();
        }
    }
    for (int j = t; j < KK; j += FTH) emit_one(b, j, sv[j], si[j], wh, reg, out);
}

extern "C" void kernel_launch(void* const* d_in, const int* in_sizes, int n_in,
                              void* d_out, int out_size, void* d_ws, size_t ws_size,
                              hipStream_t stream) {
    const float* x   = (const float*)d_in[0];
    const float* wh  = (const float*)d_in[1];
    const float* reg = (const float*)d_in[2];
    float* out = (float*)d_out;

    // workspace layout: bcnt [16][128] in first 8 KiB, done [16] at +8 KiB,
    // candidate arrays unchanged at +16 KiB (same footprint as before).
    char* ws = (char*)d_ws;
    int*   bcnt = (int*)(ws);                                        // [16][128]
    int*   done = (int*)(ws + 8 * 1024);                             // [16]
    float* cval = (float*)(ws + 16 * 1024);                          // [16][128][24]
    int*   cidx = (int*)(ws + 16 * 1024 + (size_t)Bn * BPB * SLOT * 4);

    // per-launch ticket reset (64 B; graph-capturable stream op)
    hipMemsetAsync(done, 0, Bn * sizeof(int), stream);

    dim3 grid(BPB, Bn);
    k_fused<<<grid, FTH, 0, stream>>>(x, wh, reg, done, bcnt, cval, cidx, out);
}

// Round 2
// 62.354 us; speedup vs baseline: 2.4838x; 2.4838x over previous
//
#include <hip/hip_runtime.h>
#include <stdint.h>
#include <limits.h>

// Problem constants (B, C, H, W fixed by the reference)
#define Bn      16
#define Nn      5242880            // 80*256*256 elements per batch
#define KK      100                // TOPK
#define BPB     128                // blocks per batch for the streaming pass
#define CHUNK   (Nn / BPB)         // 40960 elements per block
#define SLOT    24                 // per-block candidate capacity (mean ~1.3 @ T0=4.0)
#define NSLOTS  (BPB * SLOT)       // 3072 slots per batch
#define SPT     (NSLOTS / 256)     // 12 speculative slots per thread
#define SORTCAP 2048               // guard-path sort capacity
#define RANKCAP 256                // fast-path rank-selection capacity (mean ~166)
#define NBINS   4096               // fallback radix bins
#define T0      4.0f               // fast-path threshold (top-100 cutoff ~4.11 for N(0,1))
#define FTH     256                // k_final block size

typedef float f4v __attribute__((ext_vector_type(4)));

__device__ __forceinline__ unsigned fkey(unsigned u) {
    // monotone float->uint transform: larger float => larger key
    return (u & 0x80000000u) ? ~u : (u | 0x80000000u);
}

// ---------- pass 1: stream x once, per-block private candidate slots ---------
// (byte-identical to the 63.6 us round-0 version)
__global__ __launch_bounds__(256) void k_collect(const float* __restrict__ x,
                                                 int* __restrict__ bcnt,
                                                 float* __restrict__ cval,
                                                 int* __restrict__ cidx) {
    const int b = blockIdx.y, blk = blockIdx.x;
    __shared__ int lcnt;
    if (threadIdx.x == 0) lcnt = 0;
    __syncthreads();
    const f4v* xv = reinterpret_cast<const f4v*>(
        x + (size_t)b * Nn + (size_t)blk * CHUNK);
    const int base = blk * CHUNK;
    float* v  = cval + ((size_t)b * BPB + blk) * SLOT;
    int*   ix = cidx + ((size_t)b * BPB + blk) * SLOT;
#pragma unroll 4
    for (int j = threadIdx.x; j < CHUNK / 4; j += 256) {
        f4v f = __builtin_nontemporal_load(&xv[j]);   // streaming read, no reuse
        const float m = fmaxf(fmaxf(f.x, f.y), fmaxf(f.z, f.w));
        if (m >= T0) {                                 // ~1.3e-4 per-lane: rare
            const int i0 = base + 4 * j;
            if (f.x >= T0) { int p = atomicAdd(&lcnt, 1); if (p < SLOT) { v[p] = f.x; ix[p] = i0;     } }
            if (f.y >= T0) { int p = atomicAdd(&lcnt, 1); if (p < SLOT) { v[p] = f.y; ix[p] = i0 + 1; } }
            if (f.z >= T0) { int p = atomicAdd(&lcnt, 1); if (p < SLOT) { v[p] = f.z; ix[p] = i0 + 2; } }
            if (f.w >= T0) { int p = atomicAdd(&lcnt, 1); if (p < SLOT) { v[p] = f.w; ix[p] = i0 + 3; } }
        }
    }
    __syncthreads();
    if (threadIdx.x == 0) bcnt[b * BPB + blk] = lcnt;   // unconditional: no zeroing needed
}

// ---------- emit one detection at a given rank ----------
__device__ __forceinline__ void emit_one(int b, int rank, float val, int idx,
                                         const float* __restrict__ wh,
                                         const float* __restrict__ reg,
                                         float* __restrict__ out) {
    float* out_cls = out;                 // [16][100]
    float* out_scr = out + Bn * KK;       // [16][100]
    float* out_res = out + 2 * Bn * KK;   // [16][100][4]
    out_cls[b * KK + rank] = (float)idx * (1.0f / 65536.0f);  // exact pow2 division
    out_scr[b * KK + rank] = val;
    const int s  = idx & 65535;
    const float tys = (float)s * (1.0f / 256.0f);             // topk_indices / W (exact)
    const float txs = (float)(s & 255);                       // topk_indices % W
    // reg/wh layout [B,2,H,W]: channel-c at (b, s) = ptr[(b*2+c)*65536 + s]
    const float xo = reg[(size_t)(b * 2 + 0) * 65536 + s];
    const float yo = reg[(size_t)(b * 2 + 1) * 65536 + s];
    const float ww = wh [(size_t)(b * 2 + 0) * 65536 + s];
    const float hh = wh [(size_t)(b * 2 + 1) * 65536 + s];
    const float cx = txs + xo;
    const float cy = tys + yo;
    const float hw  = ww * 0.5f;
    const float hh2 = hh * 0.5f;
    float* r = out_res + (size_t)(b * KK + rank) * 4;
    r[0] = (cx - hw)  * 4.0f;
    r[1] = (cy - hh2) * 4.0f;
    r[2] = (cx + hw)  * 4.0f;
    r[3] = (cy + hh2) * 4.0f;
}

// ---------- pass 2: per batch, gather + rank-select + emit -------------------
__global__ __launch_bounds__(FTH) void k_final(const float* __restrict__ x,
                                               const float* __restrict__ wh,
                                               const float* __restrict__ reg,
                                               const int* __restrict__ bcnt,
                                               const float* __restrict__ cval,
                                               const int* __restrict__ cidx,
                                               float* __restrict__ out) {
    const int b = blockIdx.x;
    const int t = threadIdx.x;
    __shared__ float sv[SORTCAP];
    __shared__ int   si[SORTCAP];
    __shared__ int   scan[BPB];
    __shared__ int   cnt[BPB];
    __shared__ int   wtot[2];
    __shared__ unsigned long long keys[RANKCAP];   // fast-path packed (val,idx)
    __shared__ int   hist[NBINS];     // fallback only
    __shared__ int   sflags;
    __shared__ int   scnt;
    __shared__ unsigned stk;

    // ---- speculative slot prefetch: overlap gather latency with the scan ----
    // All 3072 slots loaded coalesced into registers before counts are known.
    float spv[SPT]; int spi[SPT];
    {
        const float* vb = cval + (size_t)b * NSLOTS;
        const int*   ib = cidx + (size_t)b * NSLOTS;
#pragma unroll
        for (int i2 = 0; i2 < SPT; ++i2) {
            const int s = t + FTH * i2;
            spv[i2] = vb[s];
            spi[i2] = ib[s];
        }
    }

    if (t == 0) { sflags = 0; scnt = 0; }

    // ---- 2-wave shuffle scan over BPB=128 counts (2 barriers, no HS ping-pong)
    int myscan = 0, myc = 0;
    if (t < BPB) {
        myc = bcnt[b * BPB + t];
        if (myc > SLOT) atomicOr(&sflags, 1);
        cnt[t] = myc;
        int v = myc;
#pragma unroll
        for (int d = 1; d < 64; d <<= 1) {
            int u = __shfl_up(v, d);
            if ((t & 63) >= d) v += u;
        }
        if ((t & 63) == 63) wtot[t >> 6] = v;
        myscan = v;
    }
    __syncthreads();
    if (t < BPB) scan[t] = myscan + ((t >= 64) ? wtot[0] : 0);
    __syncthreads();

    const int total_all = scan[BPB - 1];
    const bool bad = (sflags != 0) || (total_all < KK) || (total_all > SORTCAP);

    const float NEG_INF = __int_as_float(0xFF800000);

    if (!bad && total_all <= RANKCAP) {
        // ---- fast path: packed u64 keys + O(n^2) broadcast rank --------------
        keys[t] = 0ull;                 // pad: smaller than any real key
        __syncthreads();
#pragma unroll
        for (int i2 = 0; i2 < SPT; ++i2) {
            const int s = t + FTH * i2;
            const int blk2 = s / SLOT, pos = s % SLOT;
            const int cc = cnt[blk2];
            if (pos < cc) {
                const int dest = scan[blk2] - cc + pos;   // exclusive prefix + pos
                keys[dest] = ((unsigned long long)fkey(__float_as_uint(spv[i2])) << 32)
                           | (unsigned)(~spi[i2]);        // val desc, idx asc
            }
        }
        __syncthreads();
        const unsigned long long myk = keys[t];
        int rank = 0;
#pragma unroll 8
        for (int j = 0; j < RANKCAP; ++j)
            rank += (keys[j] > myk) ? 1 : 0;              // 1x ds_read_b64 broadcast
        if (rank < KK) {
            const unsigned hi = (unsigned)(myk >> 32);
            const unsigned ub = (hi & 0x80000000u) ? (hi & 0x7FFFFFFFu) : ~hi; // exact inverse of fkey
            emit_one(b, rank, __uint_as_float(ub), (int)~(unsigned)myk, wh, reg, out);
        }
        return;
    }

    int n;
    if (!bad) {
        // ---- guard path setup: place speculative registers into sv/si -------
        n = total_all;
        for (int i = t; i < SORTCAP; i += FTH) { sv[i] = NEG_INF; si[i] = INT_MAX; }
        __syncthreads();
#pragma unroll
        for (int i2 = 0; i2 < SPT; ++i2) {
            const int s = t + FTH * i2;
            const int blk2 = s / SLOT, pos = s % SLOT;
            const int cc = cnt[blk2];
            if (pos < cc) {
                const int dest = scan[blk2] - cc + pos;
                sv[dest] = spv[i2]; si[dest] = spi[i2];
            }
        }
        __syncthreads();
    } else {
        // ---- robust fallback: LDS-histogram top-k over full batch (never-path)
        for (int i = t; i < NBINS; i += FTH) hist[i] = 0;
        for (int i = t; i < SORTCAP; i += FTH) { sv[i] = NEG_INF; si[i] = INT_MAX; }
        __syncthreads();
        const float4* xv = reinterpret_cast<const float4*>(x + (size_t)b * Nn);
        for (int j = t; j < Nn / 4; j += FTH) {
            float4 f = xv[j];
            atomicAdd(&hist[fkey(__float_as_uint(f.x)) >> 20], 1);
            atomicAdd(&hist[fkey(__float_as_uint(f.y)) >> 20], 1);
            atomicAdd(&hist[fkey(__float_as_uint(f.z)) >> 20], 1);
            atomicAdd(&hist[fkey(__float_as_uint(f.w)) >> 20], 1);
        }
        __syncthreads();
        if (t == 0) {
            int cum = 0; unsigned k = 0;
            for (int bin = NBINS - 1; bin >= 0; --bin) {
                cum += hist[bin];
                if (cum >= KK) { k = (unsigned)bin << 20; break; }
            }
            stk = k;
        }
        __syncthreads();
        const unsigned tk = stk;
        for (int j = t; j < Nn / 4; j += FTH) {
            float4 f = xv[j];
            const int i0 = 4 * j;
            float a[4] = {f.x, f.y, f.z, f.w};
#pragma unroll
            for (int cc = 0; cc < 4; ++cc) {
                if (fkey(__float_as_uint(a[cc])) >= tk) {
                    int p = atomicAdd(&scnt, 1);
                    if (p < SORTCAP) { sv[p] = a[cc]; si[p] = i0 + cc; }
                }
            }
        }
        __syncthreads();
        n = scnt; if (n > SORTCAP) n = SORTCAP;
    }

    // ---- guard path: bitonic sort (value desc, tie -> index asc) ------------
    int pad = FTH;
    while (pad < n) pad <<= 1;     // <= SORTCAP
    for (int k = 2; k <= pad; k <<= 1) {
        for (int j = k >> 1; j > 0; j >>= 1) {
            for (int i = t; i < pad; i += FTH) {
                const int ixj = i ^ j;
                if (ixj > i) {
                    float va = sv[i], vb = sv[ixj];
                    int   ia = si[i], ib = si[ixj];
                    const bool a_before_b = (va > vb) || (va == vb && ia < ib);
                    const bool dir = ((i & k) == 0);
                    if (dir ? !a_before_b : a_before_b) {
                        sv[i] = vb; sv[ixj] = va; si[i] = ib; si[ixj] = ia;
                    }
                }
            }
            __syncthreads();
        }
    }
    for (int j = t; j < KK; j += FTH) emit_one(b, j, sv[j], si[j], wh, reg, out);
}

extern "C" void kernel_launch(void* const* d_in, const int* in_sizes, int n_in,
                              void* d_out, int out_size, void* d_ws, size_t ws_size,
                              hipStream_t stream) {
    const float* x   = (const float*)d_in[0];
    const float* wh  = (const float*)d_in[1];
    const float* reg = (const float*)d_in[2];
    float* out = (float*)d_out;

    // workspace layout (no zero-initialization required anywhere)
    char* ws = (char*)d_ws;
    int*   bcnt = (int*)(ws);                                        // [16][128]
    float* cval = (float*)(ws + 16 * 1024);                          // [16][128][24]
    int*   cidx = (int*)(ws + 16 * 1024 + (size_t)Bn * BPB * SLOT * 4);

    dim3 gridS(BPB, Bn);
    k_collect<<<gridS, 256, 0, stream>>>(x, bcnt, cval, cidx);
    k_final  <<<Bn,    FTH, 0, stream>>>(x, wh, reg, bcnt, cval, cidx, out);
}